// Round 2
// baseline (27992.993 us; speedup 1.0000x reference)
//
#include <hip/hip_runtime.h>
#include <hip/hip_bf16.h>

#define B 128
#define P 196
#define ENC 512
#define DEC 512
#define ATT 256
#define EMB 256
#define V 5000
#define S 256
#define S1 257
#define NG 2048      // 4*DEC
#define KS 16        // k-splits for gates GEMM

// ---------------- mean over P ----------------
__global__ __launch_bounds__(256) void k_mean(const float* __restrict__ feat,
                                              float* __restrict__ mean_f) {
    int idx = blockIdx.x * 256 + threadIdx.x;     // over B*ENC
    int b = idx >> 9, e = idx & 511;
    const float* fp = feat + (size_t)b * P * ENC + e;
    float s = 0.f;
    for (int p = 0; p < P; ++p) s += fp[(size_t)p * ENC];
    mean_f[idx] = s * (1.0f / (float)P);
}

// ---------------- h0 / c0 ----------------
__global__ __launch_bounds__(256) void k_init_hc(const float* __restrict__ mean_f,
        const float* __restrict__ ih_w, const float* __restrict__ ih_b,
        const float* __restrict__ ic_w, const float* __restrict__ ic_b,
        float* __restrict__ h, float* __restrict__ c) {
    int idx = blockIdx.x * 256 + threadIdx.x;     // over B*DEC
    int b = idx >> 9, d = idx & 511;
    const float* mf = mean_f + (size_t)b * ENC;
    float sh = ih_b[d], sc = ic_b[d];
    for (int e = 0; e < ENC; ++e) {
        float m = mf[e];
        sh = fmaf(m, ih_w[(size_t)e * DEC + d], sh);
        sc = fmaf(m, ic_w[(size_t)e * DEC + d], sc);
    }
    h[idx] = sh; c[idx] = sc;
}

// ---------------- Uf = features @ Ua_w + Ua_b ----------------
__global__ __launch_bounds__(256) void k_uf(const float* __restrict__ feat,
        const float* __restrict__ Ua_w, const float* __restrict__ Ua_b,
        float* __restrict__ Uf) {
    int row0 = blockIdx.x * 8;                    // bp row base (B*P rows)
    int a = threadIdx.x;                          // 0..255 == ATT
    __shared__ float fs[8][ENC];
    for (int i = threadIdx.x; i < 8 * ENC; i += 256) {
        int r = i >> 9, e = i & 511;
        fs[r][e] = feat[(size_t)(row0 + r) * ENC + e];
    }
    __syncthreads();
    float acc[8];
    float bia = Ua_b[a];
#pragma unroll
    for (int r = 0; r < 8; ++r) acc[r] = bia;
    for (int e = 0; e < ENC; ++e) {
        float w = Ua_w[(size_t)e * ATT + a];
#pragma unroll
        for (int r = 0; r < 8; ++r) acc[r] = fmaf(fs[r][e], w, acc[r]);
    }
#pragma unroll
    for (int r = 0; r < 8; ++r) Uf[(size_t)(row0 + r) * ATT + a] = acc[r];
}

// ---------------- Gemb = embeds[:, :S] @ W_ih[:EMB]  (bf16 out) ----------------
__global__ __launch_bounds__(256) void k_gemb(const float* __restrict__ emb,
        const int* __restrict__ captions, const float* __restrict__ W_ih,
        __hip_bfloat16* __restrict__ Gemb) {
    __shared__ float As[16][128];
    __shared__ float Bs[16][128];
    __shared__ int rowcap[128];
    int m0 = blockIdx.x * 128;                    // rows m = t*B + b
    int n0 = blockIdx.y * 128;
    int tid = threadIdx.x;
    if (tid < 128) {
        int m = m0 + tid;
        rowcap[tid] = captions[(size_t)(m & 127) * S1 + (m >> 7)];
    }
    __syncthreads();
    int tx = tid & 15, ty = tid >> 4;
    float acc[8][8];
#pragma unroll
    for (int i = 0; i < 8; ++i)
#pragma unroll
        for (int j = 0; j < 8; ++j) acc[i][j] = 0.f;
    int arow = tid >> 1, ak = (tid & 1) * 8;
    int bkk = tid >> 4, bn = (tid & 15) * 8;
    for (int k0 = 0; k0 < EMB; k0 += 16) {
        {
            const float* ap = emb + (size_t)rowcap[arow] * EMB + k0 + ak;
            float4 v0 = *(const float4*)ap;
            float4 v1 = *(const float4*)(ap + 4);
            As[ak + 0][arow] = v0.x; As[ak + 1][arow] = v0.y;
            As[ak + 2][arow] = v0.z; As[ak + 3][arow] = v0.w;
            As[ak + 4][arow] = v1.x; As[ak + 5][arow] = v1.y;
            As[ak + 6][arow] = v1.z; As[ak + 7][arow] = v1.w;
        }
        {
            const float* bp = W_ih + (size_t)(k0 + bkk) * NG + n0 + bn;
            *(float4*)&Bs[bkk][bn] = *(const float4*)bp;
            *(float4*)&Bs[bkk][bn + 4] = *(const float4*)(bp + 4);
        }
        __syncthreads();
#pragma unroll
        for (int kk = 0; kk < 16; ++kk) {
            float4 a0 = *(const float4*)&As[kk][ty * 8];
            float4 a1 = *(const float4*)&As[kk][ty * 8 + 4];
            float4 b0 = *(const float4*)&Bs[kk][tx * 8];
            float4 b1 = *(const float4*)&Bs[kk][tx * 8 + 4];
            float av[8] = {a0.x, a0.y, a0.z, a0.w, a1.x, a1.y, a1.z, a1.w};
            float bv[8] = {b0.x, b0.y, b0.z, b0.w, b1.x, b1.y, b1.z, b1.w};
#pragma unroll
            for (int i = 0; i < 8; ++i)
#pragma unroll
                for (int j = 0; j < 8; ++j)
                    acc[i][j] = fmaf(av[i], bv[j], acc[i][j]);
        }
        __syncthreads();
    }
#pragma unroll
    for (int i = 0; i < 8; ++i) {
        __hip_bfloat16* gp = Gemb + (size_t)(m0 + ty * 8 + i) * NG + n0 + tx * 8;
#pragma unroll
        for (int j = 0; j < 8; ++j) gp[j] = __float2bfloat16(acc[i][j]);
    }
}

// ---------------- fused: [reduce partials + LSTM cell] then attention ----------------
// t==0: no cell (h from init). t==S: cell only, no attention.
__global__ __launch_bounds__(256) void k_attn_cell(
        const float* __restrict__ partials, const __hip_bfloat16* __restrict__ Gemb,
        const float* __restrict__ b_ih, const float* __restrict__ b_hh,
        float* __restrict__ h, float* __restrict__ c, float* __restrict__ Hall,
        const float* __restrict__ Uf, const float* __restrict__ feat,
        const float* __restrict__ Wa_w, const float* __restrict__ Wa_b,
        const float* __restrict__ va_w, const float* __restrict__ va_b,
        float* __restrict__ ctx, int t, int use_gemb, int use_hall) {
    int b = blockIdx.x;
    int tid = threadIdx.x;
    __shared__ float hs[DEC];
    __shared__ float wah[ATT];
    __shared__ float sc[P];
    __shared__ float red[8];

    if (t > 0) {
        float s[2][4];
#pragma unroll
        for (int j = 0; j < 2; ++j)
#pragma unroll
            for (int q = 0; q < 4; ++q) {
                int n = q * DEC + j * 256 + tid;
                s[j][q] = b_ih[n] + b_hh[n];
            }
        for (int ks = 0; ks < KS; ++ks) {
            const float* pp = partials + ((size_t)ks * B + b) * NG;
#pragma unroll
            for (int j = 0; j < 2; ++j)
#pragma unroll
                for (int q = 0; q < 4; ++q)
                    s[j][q] += pp[q * DEC + j * 256 + tid];
        }
        if (use_gemb) {
            const __hip_bfloat16* gp = Gemb + ((size_t)(t - 1) * B + b) * NG;
#pragma unroll
            for (int j = 0; j < 2; ++j)
#pragma unroll
                for (int q = 0; q < 4; ++q)
                    s[j][q] += __bfloat162float(gp[q * DEC + j * 256 + tid]);
        }
#pragma unroll
        for (int j = 0; j < 2; ++j) {
            int d = j * 256 + tid;
            float ii = 1.f / (1.f + __expf(-s[j][0]));
            float ff = 1.f / (1.f + __expf(-s[j][1]));
            float gg = tanhf(s[j][2]);
            float oo = 1.f / (1.f + __expf(-s[j][3]));
            size_t idx = (size_t)b * DEC + d;
            float cn = ff * c[idx] + ii * gg;
            float hn = oo * tanhf(cn);
            c[idx] = cn; h[idx] = hn; hs[d] = hn;
            if (use_hall) Hall[((size_t)(t - 1) * B + b) * DEC + d] = hn;
        }
    } else {
        for (int d = tid; d < DEC; d += 256) hs[d] = h[(size_t)b * DEC + d];
    }
    if (t == S) return;
    __syncthreads();

    {   // wah[a] = Wa_b[a] + sum_d hs[d]*Wa_w[d,a]
        int a = tid;
        float ssum = Wa_b[a];
#pragma unroll 4
        for (int d = 0; d < DEC; ++d) ssum = fmaf(hs[d], Wa_w[(size_t)d * ATT + a], ssum);
        wah[a] = ssum;
    }
    __syncthreads();
    int wave = tid >> 6, lane = tid & 63;
    const float vb = va_b[0];
    for (int p = wave; p < P; p += 4) {
        const float* ufp = Uf + ((size_t)b * P + p) * ATT + lane * 4;
        float4 u = *(const float4*)ufp;
        float4 w4 = *(const float4*)&wah[lane * 4];
        float4 v4 = *(const float4*)&va_w[lane * 4];
        float ssc = v4.x * tanhf(u.x + w4.x) + v4.y * tanhf(u.y + w4.y)
                  + v4.z * tanhf(u.z + w4.z) + v4.w * tanhf(u.w + w4.w);
#pragma unroll
        for (int off = 32; off; off >>= 1) ssc += __shfl_down(ssc, off);
        if (lane == 0) sc[p] = ssc + vb;
    }
    __syncthreads();
    float v = (tid < P) ? sc[tid] : -1e30f;
    float m = v;
#pragma unroll
    for (int off = 32; off; off >>= 1) m = fmaxf(m, __shfl_down(m, off));
    if (lane == 0) red[wave] = m;
    __syncthreads();
    if (tid == 0) red[4] = fmaxf(fmaxf(red[0], red[1]), fmaxf(red[2], red[3]));
    __syncthreads();
    float mm = red[4];
    float e = (tid < P) ? __expf(v - mm) : 0.f;
    float ssum = e;
#pragma unroll
    for (int off = 32; off; off >>= 1) ssum += __shfl_down(ssum, off);
    if (lane == 0) red[wave] = ssum;
    __syncthreads();
    if (tid == 0) red[5] = 1.0f / (red[0] + red[1] + red[2] + red[3]);
    __syncthreads();
    float inv = red[5];
    if (tid < P) sc[tid] = e * inv;
    __syncthreads();
    float acc0 = 0.f, acc1 = 0.f;
    const float* fb = feat + (size_t)b * P * ENC;
    for (int p = 0; p < P; ++p) {
        float al = sc[p];
        acc0 = fmaf(al, fb[(size_t)p * ENC + tid], acc0);
        acc1 = fmaf(al, fb[(size_t)p * ENC + tid + 256], acc1);
    }
    ctx[(size_t)b * ENC + tid] = acc0;
    ctx[(size_t)b * ENC + tid + 256] = acc1;
}

// ---------------- gates partial GEMM: grid (32 n-tiles of 64, KS k-splits) ----------------
// use_gemb: K=1024 over [ctx(512), h(512)], kch=64
// else:     K=1280 over [emb(256), ctx(512), h(512)], kch=80
__global__ __launch_bounds__(256) void k_gates(const float* __restrict__ emb,
        const int* __restrict__ captions, int t,
        const float* __restrict__ ctx, const float* __restrict__ h,
        const float* __restrict__ W_ih, const float* __restrict__ W_hh,
        float* __restrict__ partials, int kch, int use_gemb) {
    __shared__ float As[16][128];
    __shared__ float Bs[16][64];
    __shared__ int scap[B];
    int n0 = blockIdx.x * 64;
    int ks = blockIdx.y;
    int tid = threadIdx.x;
    if (!use_gemb && tid < B) scap[tid] = captions[(size_t)tid * S1 + t];
    __syncthreads();
    int tx = tid & 15, ty = tid >> 4;
    float acc[8][4];
#pragma unroll
    for (int i = 0; i < 8; ++i)
#pragma unroll
        for (int j = 0; j < 4; ++j) acc[i][j] = 0.f;
    int arow = tid >> 1, ak = (tid & 1) * 8;
    int bkk = tid >> 4, bn = (tid & 15) * 4;
    for (int k0 = ks * kch; k0 < ks * kch + kch; k0 += 16) {
        const float* ap;
        if (use_gemb) {
            ap = (k0 < ENC) ? ctx + (size_t)arow * ENC + k0
                            : h + (size_t)arow * DEC + (k0 - ENC);
        } else {
            if (k0 < EMB)            ap = emb + (size_t)scap[arow] * EMB + k0;
            else if (k0 < EMB + ENC) ap = ctx + (size_t)arow * ENC + (k0 - EMB);
            else                     ap = h + (size_t)arow * DEC + (k0 - EMB - ENC);
        }
        float4 v0 = *(const float4*)(ap + ak);
        float4 v1 = *(const float4*)(ap + ak + 4);
        As[ak + 0][arow] = v0.x; As[ak + 1][arow] = v0.y;
        As[ak + 2][arow] = v0.z; As[ak + 3][arow] = v0.w;
        As[ak + 4][arow] = v1.x; As[ak + 5][arow] = v1.y;
        As[ak + 6][arow] = v1.z; As[ak + 7][arow] = v1.w;
        int k = k0 + bkk;
        const float* bp;
        if (use_gemb) {
            bp = (k < ENC) ? W_ih + (size_t)(k + EMB) * NG + n0 + bn
                           : W_hh + (size_t)(k - ENC) * NG + n0 + bn;
        } else {
            bp = (k < EMB + ENC) ? W_ih + (size_t)k * NG + n0 + bn
                                 : W_hh + (size_t)(k - EMB - ENC) * NG + n0 + bn;
        }
        *(float4*)&Bs[bkk][bn] = *(const float4*)bp;
        __syncthreads();
#pragma unroll
        for (int kk = 0; kk < 16; ++kk) {
            float4 a0 = *(const float4*)&As[kk][ty * 8];
            float4 a1 = *(const float4*)&As[kk][ty * 8 + 4];
            float4 b0 = *(const float4*)&Bs[kk][tx * 4];
            float av[8] = {a0.x, a0.y, a0.z, a0.w, a1.x, a1.y, a1.z, a1.w};
            float bv[4] = {b0.x, b0.y, b0.z, b0.w};
#pragma unroll
            for (int i = 0; i < 8; ++i)
#pragma unroll
                for (int j = 0; j < 4; ++j)
                    acc[i][j] = fmaf(av[i], bv[j], acc[i][j]);
        }
        __syncthreads();
    }
#pragma unroll
    for (int i = 0; i < 8; ++i) {
        int mrow = ty * 8 + i;
        float* pp = partials + ((size_t)ks * B + mrow) * NG + n0 + tx * 4;
        *(float4*)pp = make_float4(acc[i][0], acc[i][1], acc[i][2], acc[i][3]);
    }
}

// ---------------- output projection GEMM ----------------
__global__ __launch_bounds__(256) void k_fcn(const float* __restrict__ A,
        const float* __restrict__ Bw, const float* __restrict__ bias,
        float* __restrict__ out, int t_fix) {
    __shared__ float As[16][128];
    __shared__ float Bs[16][128];
    int m0 = blockIdx.x * 128;
    int n0 = blockIdx.y * 128;
    int tid = threadIdx.x;
    int tx = tid & 15, ty = tid >> 4;
    float acc[8][8];
#pragma unroll
    for (int i = 0; i < 8; ++i)
#pragma unroll
        for (int j = 0; j < 8; ++j) acc[i][j] = 0.f;
    int arow = tid >> 1, ak = (tid & 1) * 8;
    int bkk = tid >> 4, bn = (tid & 15) * 8;
    const float4 z4 = make_float4(0.f, 0.f, 0.f, 0.f);
    for (int k0 = 0; k0 < DEC; k0 += 16) {
        {
            const float* ap = A + (size_t)(m0 + arow) * DEC + k0 + ak;
            float4 v0 = *(const float4*)ap;
            float4 v1 = *(const float4*)(ap + 4);
            As[ak + 0][arow] = v0.x; As[ak + 1][arow] = v0.y;
            As[ak + 2][arow] = v0.z; As[ak + 3][arow] = v0.w;
            As[ak + 4][arow] = v1.x; As[ak + 5][arow] = v1.y;
            As[ak + 6][arow] = v1.z; As[ak + 7][arow] = v1.w;
        }
        {
            int n4 = n0 + bn;
            const float* bp = Bw + (size_t)(k0 + bkk) * V + n4;
            float4 v0 = (n4 < V) ? *(const float4*)bp : z4;
            float4 v1 = (n4 + 4 < V) ? *(const float4*)(bp + 4) : z4;
            *(float4*)&Bs[bkk][bn] = v0;
            *(float4*)&Bs[bkk][bn + 4] = v1;
        }
        __syncthreads();
#pragma unroll
        for (int kk = 0; kk < 16; ++kk) {
            float4 a0 = *(const float4*)&As[kk][ty * 8];
            float4 a1 = *(const float4*)&As[kk][ty * 8 + 4];
            float4 b0 = *(const float4*)&Bs[kk][tx * 8];
            float4 b1 = *(const float4*)&Bs[kk][tx * 8 + 4];
            float av[8] = {a0.x, a0.y, a0.z, a0.w, a1.x, a1.y, a1.z, a1.w};
            float bv[8] = {b0.x, b0.y, b0.z, b0.w, b1.x, b1.y, b1.z, b1.w};
#pragma unroll
            for (int i = 0; i < 8; ++i)
#pragma unroll
                for (int j = 0; j < 8; ++j)
                    acc[i][j] = fmaf(av[i], bv[j], acc[i][j]);
        }
        __syncthreads();
    }
#pragma unroll
    for (int i = 0; i < 8; ++i) {
        int mrow = m0 + ty * 8 + i;
        int bb, tt;
        if (t_fix >= 0) { bb = mrow; tt = t_fix; }
        else            { tt = mrow >> 7; bb = mrow & 127; }
        float* op = out + ((size_t)bb * S + tt) * V + n0 + tx * 8;
#pragma unroll
        for (int j = 0; j < 8; ++j) {
            int n = n0 + tx * 8 + j;
            if (n < V) op[j] = acc[i][j] + bias[n];
        }
    }
}

extern "C" void kernel_launch(void* const* d_in, const int* in_sizes, int n_in,
                              void* d_out, int out_size, void* d_ws, size_t ws_size,
                              hipStream_t stream) {
    const float* features = (const float*)d_in[0];
    const int*   captions = (const int*)d_in[1];
    const float* emb      = (const float*)d_in[2];
    const float* Ua_w     = (const float*)d_in[3];
    const float* Ua_b     = (const float*)d_in[4];
    const float* Wa_w     = (const float*)d_in[5];
    const float* Wa_b     = (const float*)d_in[6];
    const float* va_w     = (const float*)d_in[7];
    const float* va_b     = (const float*)d_in[8];
    const float* ih_w     = (const float*)d_in[9];
    const float* ih_b     = (const float*)d_in[10];
    const float* ic_w     = (const float*)d_in[11];
    const float* ic_b     = (const float*)d_in[12];
    const float* W_ih     = (const float*)d_in[13];
    const float* b_ih     = (const float*)d_in[14];
    const float* W_hh     = (const float*)d_in[15];
    const float* b_hh     = (const float*)d_in[16];
    const float* fcn_w    = (const float*)d_in[17];
    const float* fcn_b    = (const float*)d_in[18];
    float* out = (float*)d_out;
    char* wsb  = (char*)d_ws;

    size_t off = 0;
    float* Uf       = (float*)(wsb + off); off += (size_t)B * P * ATT * 4;   // 25.7MB
    float* partials = (float*)(wsb + off); off += (size_t)KS * B * NG * 4;   // 16.8MB
    float* hbuf     = (float*)(wsb + off); off += (size_t)B * DEC * 4;
    float* cbuf     = (float*)(wsb + off); off += (size_t)B * DEC * 4;
    float* ctx      = (float*)(wsb + off); off += (size_t)B * ENC * 4;
    float* meanf    = (float*)(wsb + off); off += (size_t)B * ENC * 4;
    float* Hall     = (float*)(wsb + off); off += (size_t)S * B * DEC * 4;   // 67MB
    size_t need_hall = off;
    __hip_bfloat16* Gemb = (__hip_bfloat16*)(wsb + off);
    off += (size_t)S * B * NG * 2;                                           // 134MB
    size_t need_gemb = off;

    int use_hall = ws_size >= need_hall;
    int use_gemb = ws_size >= need_gemb;
    int kch = use_gemb ? 64 : 80;   // K=1024 vs 1280, over KS=16 splits

    k_mean<<<256, 256, 0, stream>>>(features, meanf);
    k_init_hc<<<256, 256, 0, stream>>>(meanf, ih_w, ih_b, ic_w, ic_b, hbuf, cbuf);
    k_uf<<<3136, 256, 0, stream>>>(features, Ua_w, Ua_b, Uf);
    if (use_gemb)
        k_gemb<<<dim3(256, 16), 256, 0, stream>>>(emb, captions, W_ih, Gemb);

    for (int t = 0; t <= S; ++t) {
        k_attn_cell<<<128, 256, 0, stream>>>(partials, Gemb, b_ih, b_hh,
                hbuf, cbuf, Hall, Uf, features, Wa_w, Wa_b, va_w, va_b,
                ctx, t, use_gemb, use_hall);
        if (t < S)
            k_gates<<<dim3(32, KS), 256, 0, stream>>>(emb, captions, t, ctx, hbuf,
                    W_ih, W_hh, partials, kch, use_gemb);
        if (!use_hall && t > 0)
            k_fcn<<<dim3(1, 40), 256, 0, stream>>>(hbuf, fcn_w, fcn_b, out, t - 1);
    }
    if (use_hall)
        k_fcn<<<dim3(256, 40), 256, 0, stream>>>(Hall, fcn_w, fcn_b, out, -1);
}